// Round 5
// baseline (1529.611 us; speedup 1.0000x reference)
//
#include <hip/hip_runtime.h>
#include <hip/hip_bf16.h>

typedef __bf16 bf16_t;
typedef __bf16 bf16x4 __attribute__((ext_vector_type(4)));
typedef __bf16 bf16x8 __attribute__((ext_vector_type(8)));
typedef float f32x4 __attribute__((ext_vector_type(4)));

#define S_ 2048
#define D_ 4096
#define H_ 32
#define KVH_ 8
#define DH_ 128
#define HID_ 11008
#define QKV_N 6144   // 4096 q + 1024 k + 1024 v
#define GU_N 22016   // 11008 g + 11008 u

__device__ __forceinline__ void gl16(const bf16_t* g, bf16_t* l) {
  __builtin_amdgcn_global_load_lds(
      (const __attribute__((address_space(1))) unsigned int*)g,
      (__attribute__((address_space(3))) unsigned int*)l, 16, 0, 0);
}

// ---------------------------------------------------------------- RMSNorm ----
__global__ __launch_bounds__(256) void rmsnorm_kernel(
    const float* __restrict__ x, const float* __restrict__ w,
    bf16_t* __restrict__ out) {
  int row = blockIdx.x;
  const float* xr = x + (size_t)row * D_;
  float ss = 0.f;
  #pragma unroll
  for (int it = 0; it < 4; ++it) {
    int i = threadIdx.x * 4 + it * 1024;
    float4 v = *(const float4*)(xr + i);
    ss += v.x * v.x + v.y * v.y + v.z * v.z + v.w * v.w;
  }
  #pragma unroll
  for (int off = 32; off; off >>= 1) ss += __shfl_xor(ss, off);
  __shared__ float s4[4];
  if ((threadIdx.x & 63) == 0) s4[threadIdx.x >> 6] = ss;
  __syncthreads();
  float tot = s4[0] + s4[1] + s4[2] + s4[3];
  float rinv = rsqrtf(tot / (float)D_ + 1e-5f);
  bf16_t* orow = out + (size_t)row * D_;
  #pragma unroll
  for (int it = 0; it < 4; ++it) {
    int i = threadIdx.x * 4 + it * 1024;
    float4 v = *(const float4*)(xr + i);
    orow[i + 0] = (bf16_t)(v.x * rinv * w[i + 0]);
    orow[i + 1] = (bf16_t)(v.y * rinv * w[i + 1]);
    orow[i + 2] = (bf16_t)(v.z * rinv * w[i + 2]);
    orow[i + 3] = (bf16_t)(v.w * rinv * w[i + 3]);
  }
}

// ----------------------- combine wo-partials + residual + RMSNorm ------------
__global__ __launch_bounds__(256) void combine_rms_kernel(
    const float* __restrict__ x, const float* __restrict__ p0,
    const float* __restrict__ p1, const float* __restrict__ w,
    float* __restrict__ x1, bf16_t* __restrict__ out) {
  int row = blockIdx.x;
  size_t base = (size_t)row * D_;
  float ss = 0.f;
  float4 vals[4];
  #pragma unroll
  for (int it = 0; it < 4; ++it) {
    int i = threadIdx.x * 4 + it * 1024;
    float4 a = *(const float4*)(x + base + i);
    float4 b = *(const float4*)(p0 + base + i);
    float4 c = *(const float4*)(p1 + base + i);
    float4 v;
    v.x = a.x + b.x + c.x; v.y = a.y + b.y + c.y;
    v.z = a.z + b.z + c.z; v.w = a.w + b.w + c.w;
    vals[it] = v;
    *(float4*)(x1 + base + i) = v;
    ss += v.x * v.x + v.y * v.y + v.z * v.z + v.w * v.w;
  }
  #pragma unroll
  for (int off = 32; off; off >>= 1) ss += __shfl_xor(ss, off);
  __shared__ float s4[4];
  if ((threadIdx.x & 63) == 0) s4[threadIdx.x >> 6] = ss;
  __syncthreads();
  float tot = s4[0] + s4[1] + s4[2] + s4[3];
  float rinv = rsqrtf(tot / (float)D_ + 1e-5f);
  #pragma unroll
  for (int it = 0; it < 4; ++it) {
    int i = threadIdx.x * 4 + it * 1024;
    float4 v = vals[it];
    out[base + i + 0] = (bf16_t)(v.x * rinv * w[i + 0]);
    out[base + i + 1] = (bf16_t)(v.y * rinv * w[i + 1]);
    out[base + i + 2] = (bf16_t)(v.z * rinv * w[i + 2]);
    out[base + i + 3] = (bf16_t)(v.w * rinv * w[i + 3]);
  }
}

// ----------------------------- combine w2-partials + residual -> d_out -------
__global__ __launch_bounds__(256) void combine_out_kernel(
    const float* __restrict__ x1, const float* __restrict__ p0,
    const float* __restrict__ p1, float* __restrict__ outp) {
  size_t i = ((size_t)blockIdx.x * 256 + threadIdx.x) * 4;
  float4 a = *(const float4*)(x1 + i);
  float4 b = *(const float4*)(p0 + i);
  float4 c = *(const float4*)(p1 + i);
  float4 v;
  v.x = a.x + b.x + c.x; v.y = a.y + b.y + c.y;
  v.z = a.z + b.z + c.z; v.w = a.w + b.w + c.w;
  *(float4*)(outp + i) = v;
}

// ------------------------------------------- weight transpose f32 -> bf16 ----
// [32][258] pad: 129-word row stride == 1 mod 32 -> conflict-free gather reads
__global__ __launch_bounds__(256) void wtrans_kernel(
    const float* __restrict__ W, bf16_t* __restrict__ WT, int K, int N) {
  __shared__ bf16_t t[32][258];
  int k0 = blockIdx.x * 32, n0 = blockIdx.y * 256;
  #pragma unroll
  for (int i = 0; i < 8; ++i) {
    int flat = i * 1024 + threadIdx.x * 4;
    int kk = flat >> 8, nn = flat & 255;
    float4 wv = *(const float4*)(W + (size_t)(k0 + kk) * N + n0 + nn);
    bf16_t* p = &t[kk][nn];
    p[0] = (bf16_t)wv.x; p[1] = (bf16_t)wv.y;
    p[2] = (bf16_t)wv.z; p[3] = (bf16_t)wv.w;
  }
  __syncthreads();
  int kc8 = (threadIdx.x & 3) * 8;
  #pragma unroll
  for (int i = 0; i < 4; ++i) {
    int nn = i * 64 + (threadIdx.x >> 2);
    bf16x8 vals;
    #pragma unroll
    for (int j = 0; j < 8; ++j) vals[j] = t[kc8 + j][nn];
    *(bf16x8*)(WT + (size_t)(n0 + nn) * K + k0 + kc8) = vals;
  }
}

// ------------------------------------------------------------- RoPE table ----
__global__ __launch_bounds__(256) void rope_table_kernel(
    const int* __restrict__ pos_ids, float* __restrict__ cos_t,
    float* __restrict__ sin_t) {
  int idx = blockIdx.x * 256 + threadIdx.x;  // S_*64
  int s = idx >> 6, i = idx & 63;
  float pos = (float)pos_ids[s];
  float inv_freq = exp2f(-(float)i * (13.287712379549449f / 64.0f));
  float ang = pos * inv_freq;
  cos_t[idx] = cosf(ang);
  sin_t[idx] = sinf(ang);
}

// --------------------------------------------- RoPE in-place on qkv buffer ---
__global__ __launch_bounds__(256) void rope_kernel(
    bf16_t* __restrict__ buf, const float* __restrict__ cos_t,
    const float* __restrict__ sin_t, int nheads, int colbase, int total) {
  int idx = blockIdx.x * 256 + threadIdx.x;
  if (idx >= total) return;
  int i = idx & 63;
  int t2 = idx >> 6;
  int s = t2 / nheads, h = t2 % nheads;
  size_t base = (size_t)s * QKV_N + colbase + h * 128 + 2 * i;
  float x1 = (float)buf[base], x2 = (float)buf[base + 1];
  float c = cos_t[s * 64 + i], sn = sin_t[s * 64 + i];
  buf[base]     = (bf16_t)(x1 * c - x2 * sn);
  buf[base + 1] = (bf16_t)(x1 * sn + x2 * c);
}

// ------------------------------------------------------- 256x256 GEMM --------
// C[2048][N] = A[2048][K+] (bf16) @ BT[N][K+] (bf16)
// MODE 0: bf16 out; MODE 2: f32 plain store (SPLIT partials).
// 8 waves (2Mx4N), BK=64, 2 K-tiles double-buffered, 4 phases/K-tile,
// counted vmcnt(8).
// LDS: each 8KB subtile [ab][h][kk] = 8 fragment blocks of 1KB, block
// b = rowhi*4+rowmid holding rows (b>>2)*64+(b&3)*16+fr, lane-ordered:
// fragment ds_read_b128 addr = block_base + lane*16B  -> zero bank conflicts.
// global_load_lds dest stays linear (tid*16B); the per-thread GLOBAL source
// is permuted to match (pre-swizzled-source pattern).

#define VMW(N)                                          \
  asm volatile("s_waitcnt vmcnt(" #N ")" ::: "memory"); \
  __builtin_amdgcn_sched_barrier(0)

#define DO_PHASE(BI, KK, MH, DO_LDB, STAGE1, STAGE2, WAITCODE)             \
  {                                                                        \
    _Pragma("unroll") for (int m = 0; m < 4; ++m)                          \
      aF[m] = *(const bf16x8*)&lds[BI][0][wr][KK]                          \
          [((MH) * 4 + m) * 512 + laneo];                                  \
    if (DO_LDB) {                                                          \
      _Pragma("unroll") for (int n = 0; n < 4; ++n)                        \
        bF[n] = *(const bf16x8*)&lds[BI][1][wcH][KK]                       \
            [(wcL * 4 + n) * 512 + laneo];                                 \
    }                                                                      \
    STAGE1;                                                                \
    STAGE2;                                                                \
    asm volatile("" ::: "memory");                                         \
    __builtin_amdgcn_s_barrier();                                          \
    asm volatile("s_waitcnt lgkmcnt(0)" ::: "memory");                     \
    __builtin_amdgcn_sched_barrier(0);                                     \
    __builtin_amdgcn_s_setprio(1);                                         \
    _Pragma("unroll") for (int m = 0; m < 4; ++m)                          \
      _Pragma("unroll") for (int n = 0; n < 4; ++n)                        \
        acc[(MH) * 4 + m][n] = __builtin_amdgcn_mfma_f32_16x16x32_bf16(    \
            aF[m], bF[n], acc[(MH) * 4 + m][n], 0, 0, 0);                  \
    __builtin_amdgcn_s_setprio(0);                                         \
    __builtin_amdgcn_sched_barrier(0);                                     \
    WAITCODE;                                                              \
    asm volatile("" ::: "memory");                                         \
    __builtin_amdgcn_s_barrier();                                          \
    asm volatile("" ::: "memory");                                         \
  }

#define DO_TILE(BI, T)                                                     \
  {                                                                        \
    const int Tp1 = (T) + 1 < NT, Tp2 = (T) + 2 < NT;                      \
    DO_PHASE(BI, 0, 0, 1,                                                  \
             if (Tp1) stage(BI ^ 1, 0, 0, 1, (T) + 1),                     \
             if (Tp1) stage(BI ^ 1, 1, 0, 1, (T) + 1), );                  \
    DO_PHASE(BI, 0, 1, 0,                                                  \
             if (Tp1) stage(BI ^ 1, 0, 1, 1, (T) + 1),                     \
             if (Tp1) stage(BI ^ 1, 1, 1, 1, (T) + 1),                     \
             if (Tp1) { VMW(8); } else { VMW(0); });                       \
    DO_PHASE(BI, 1, 0, 1,                                                  \
             if (Tp2) stage(BI, 0, 0, 0, (T) + 2),                         \
             if (Tp2) stage(BI, 1, 0, 0, (T) + 2), );                      \
    DO_PHASE(BI, 1, 1, 0,                                                  \
             if (Tp2) stage(BI, 0, 1, 0, (T) + 2),                         \
             if (Tp2) stage(BI, 1, 1, 0, (T) + 2),                         \
             if (Tp2) { VMW(8); } else if (Tp1) { VMW(4); });              \
  }

template <int MODE, int SPLIT>
__global__ __launch_bounds__(512, 2) void gemm256_kernel(
    const bf16_t* __restrict__ A, int lda, const bf16_t* __restrict__ BT,
    int ldb, void* __restrict__ Cout, int ldc, int K) {
  // [buf][A=0/B=1][half(row-block)][kk][8 blocks * 512 elems]  = 128 KiB
  __shared__ __align__(16) bf16_t lds[2][2][2][2][8 * 512];

  const int tid = threadIdx.x;
  const int lane = tid & 63;
  const int wid = tid >> 6;
  const int wr = wid >> 2;            // 0..1  (M half)
  const int wc = wid & 3;             // 0..3  (N quarter)
  const int wcH = wc >> 1, wcL = wc & 1;
  const int g = lane >> 4, fr = lane & 15;
  const int laneo = lane * 8;         // lane*16B in elems

  // XCD-aware bijective swizzle (grid % 8 == 0 for all launches)
  const int nwg = gridDim.x;
  const int orig = blockIdx.x;
  int wg = (orig & 7) * (nwg >> 3) + (orig >> 3);
  int kz = 0;
  if constexpr (SPLIT) {
    const int half = nwg >> 1;
    kz = wg >= half;
    wg -= kz * half;
  }
  const int bx = wg & 7;              // M blocks = 2048/256 = 8
  const int by = wg >> 3;
  const size_t row0 = (size_t)bx * 256, col0 = (size_t)by * 256;

  // per-thread staging source: thread tid stages fragment-block b = tid>>6,
  // lane slot (g',fr') = ((tid>>4)&3, tid&15):
  //   row  = (b>>2)*64 + (b&3)*16 + fr'
  //   kels = g'*8
  const int rowL = ((tid >> 8) & 1) * 64 + ((tid >> 6) & 3) * 16 + (tid & 15);
  const int kEl = ((tid >> 4) & 3) * 8;

  const size_t lda2 = (size_t)lda * 2, ldb2 = (size_t)ldb * 2;
  const size_t kzoff = (size_t)kz * K * 2;
  const char* aB0 =
      (const char*)A + (row0 + rowL) * lda2 + kEl * 2 + kzoff;
  const char* aB1 = aB0 + (size_t)128 * lda2;
  const char* bB0 =
      (const char*)BT + (col0 + rowL) * ldb2 + kEl * 2 + kzoff;
  const char* bB1 = bB0 + (size_t)128 * ldb2;

  auto stage = [&](int bi, int ab, int h, int kk, int kt) {
    const char* base = ab ? (h ? bB1 : bB0) : (h ? aB1 : aB0);
    gl16((const bf16_t*)(base + (size_t)kt * 128 + kk * 64),
         &lds[bi][ab][h][kk][tid * 8]);
  };

  f32x4 acc[8][4] = {};
  bf16x8 aF[4], bF[4];
  const int NT = K / 64;  // even for all our shapes

  // prologue: tile0 fully, tile1 kk0
  stage(0, 0, 0, 0, 0); stage(0, 1, 0, 0, 0);
  stage(0, 0, 1, 0, 0); stage(0, 1, 1, 0, 0);
  stage(0, 0, 0, 1, 0); stage(0, 1, 0, 1, 0);
  stage(0, 0, 1, 1, 0); stage(0, 1, 1, 1, 0);
  stage(1, 0, 0, 0, 1); stage(1, 1, 0, 0, 1);
  stage(1, 0, 1, 0, 1); stage(1, 1, 1, 0, 1);
  VMW(4);
  asm volatile("" ::: "memory");
  __builtin_amdgcn_s_barrier();
  asm volatile("" ::: "memory");

  for (int T = 0; T < NT; T += 2) {
    DO_TILE(0, T);
    DO_TILE(1, T + 1);
  }

  // epilogue
  float* fOut = (float*)Cout + (size_t)kz * 2048 * ldc;
  #pragma unroll
  for (int mf = 0; mf < 8; ++mf)
    #pragma unroll
    for (int n = 0; n < 4; ++n)
      #pragma unroll
      for (int r = 0; r < 4; ++r) {
        size_t row = row0 + wr * 128 + mf * 16 + g * 4 + r;
        size_t col = col0 + wc * 64 + n * 16 + fr;
        float val = acc[mf][n][r];
        if constexpr (MODE == 0) {
          ((bf16_t*)Cout)[row * ldc + col] = (bf16_t)val;
        } else {
          fOut[row * ldc + col] = val;
        }
      }
}

// ------------------------------------------------------- flash attention -----
__global__ __launch_bounds__(256) void attn_kernel(
    const bf16_t* __restrict__ qkv, bf16_t* __restrict__ o) {
  int h = blockIdx.y;
  int qb = blockIdx.x;
  int kvh = h >> 2;
  int wid = threadIdx.x >> 6, lane = threadIdx.x & 63;
  int g = lane >> 4, fr = lane & 15;

  __shared__ __align__(16) bf16_t k_lds[64][136];
  __shared__ __align__(16) bf16_t vt_lds[128][72];
  __shared__ __align__(16) bf16_t p_lds[4][16][72];

  int q0w = qb * 64 + wid * 16;
  bf16x8 q_frag[4];
  const bf16_t* qptr = qkv + (size_t)(q0w + fr) * QKV_N + h * 128;
  #pragma unroll
  for (int kc = 0; kc < 4; ++kc)
    q_frag[kc] = *(const bf16x8*)(qptr + kc * 32 + g * 8);

  f32x4 o_frag[8] = {};
  float m_run[4], l_run[4];
  #pragma unroll
  for (int r = 0; r < 4; ++r) { m_run[r] = -1e30f; l_run[r] = 0.f; }

  const float sc = 0.08838834764831845f * 1.4426950408889634f;

  for (int t = 0; t <= qb; ++t) {
    int kv0 = t * 64;
    __syncthreads();
    for (int i = threadIdx.x; i < 1024; i += 256) {
      int row = i >> 4, c8 = (i & 15) * 8;
      size_t base = (size_t)(kv0 + row) * QKV_N + kvh * 128 + c8;
      bf16x8 k8 = *(const bf16x8*)(qkv + base + 4096);
      *(bf16x8*)&k_lds[row][c8] = k8;
      bf16x8 v8 = *(const bf16x8*)(qkv + base + 5120);
      #pragma unroll
      for (int j = 0; j < 8; ++j) vt_lds[c8 + j][row] = v8[j];
    }
    __syncthreads();

    f32x4 sfr[4];
    #pragma unroll
    for (int nf = 0; nf < 4; ++nf) {
      f32x4 acc = {};
      #pragma unroll
      for (int kc = 0; kc < 4; ++kc) {
        bf16x8 kf = *(const bf16x8*)&k_lds[fr + 16 * nf][kc * 32 + g * 8];
        acc = __builtin_amdgcn_mfma_f32_16x16x32_bf16(q_frag[kc], kf, acc, 0, 0, 0);
      }
      sfr[nf] = acc;
    }

    bool diag = (t == qb);
    float mtile[4];
    #pragma unroll
    for (int r = 0; r < 4; ++r) mtile[r] = -1e30f;
    #pragma unroll
    for (int nf = 0; nf < 4; ++nf)
      #pragma unroll
      for (int r = 0; r < 4; ++r) {
        if (diag) {
          int kvg = kv0 + nf * 16 + fr;
          int qg = q0w + 4 * g + r;
          if (kvg > qg) sfr[nf][r] = -1e30f;
        }
        mtile[r] = fmaxf(mtile[r], sfr[nf][r]);
      }
    #pragma unroll
    for (int r = 0; r < 4; ++r) {
      float mv = mtile[r];
      mv = fmaxf(mv, __shfl_xor(mv, 1));
      mv = fmaxf(mv, __shfl_xor(mv, 2));
      mv = fmaxf(mv, __shfl_xor(mv, 4));
      mv = fmaxf(mv, __shfl_xor(mv, 8));
      mtile[r] = mv;
    }
    float alpha[4];
    #pragma unroll
    for (int r = 0; r < 4; ++r) {
      float m_new = fmaxf(m_run[r], mtile[r]);
      alpha[r] = exp2f((m_run[r] - m_new) * sc);
      m_run[r] = m_new;
    }
    float lsum[4] = {0.f, 0.f, 0.f, 0.f};
    #pragma unroll
    for (int nf = 0; nf < 4; ++nf)
      #pragma unroll
      for (int r = 0; r < 4; ++r) {
        float p = exp2f((sfr[nf][r] - m_run[r]) * sc);
        sfr[nf][r] = p;
        lsum[r] += p;
      }
    #pragma unroll
    for (int r = 0; r < 4; ++r) {
      float lv = lsum[r];
      lv += __shfl_xor(lv, 1);
      lv += __shfl_xor(lv, 2);
      lv += __shfl_xor(lv, 4);
      lv += __shfl_xor(lv, 8);
      l_run[r] = l_run[r] * alpha[r] + lv;
    }
    #pragma unroll
    for (int nfo = 0; nfo < 8; ++nfo)
      #pragma unroll
      for (int r = 0; r < 4; ++r) o_frag[nfo][r] *= alpha[r];

    #pragma unroll
    for (int nf = 0; nf < 4; ++nf)
      #pragma unroll
      for (int r = 0; r < 4; ++r)
        p_lds[wid][4 * g + r][nf * 16 + fr] = (bf16_t)sfr[nf][r];
    __syncthreads();

    #pragma unroll
    for (int kc = 0; kc < 2; ++kc) {
      bf16x8 pf = *(const bf16x8*)&p_lds[wid][fr][kc * 32 + g * 8];
      #pragma unroll
      for (int nfo = 0; nfo < 8; ++nfo) {
        bf16x8 vf = *(const bf16x8*)&vt_lds[nfo * 16 + fr][kc * 32 + g * 8];
        o_frag[nfo] = __builtin_amdgcn_mfma_f32_16x16x32_bf16(pf, vf, o_frag[nfo], 0, 0, 0);
      }
    }
  }

  #pragma unroll
  for (int nfo = 0; nfo < 8; ++nfo)
    #pragma unroll
    for (int r = 0; r < 4; ++r) {
      int qg = q0w + 4 * g + r;
      float val = o_frag[nfo][r] / l_run[r];
      o[(size_t)qg * (H_ * DH_) + h * DH_ + nfo * 16 + fr] = (bf16_t)val;
    }
}

// ---------------------------------------------- SiLU*mul in-place on gu ------
__global__ __launch_bounds__(256) void silu_mul_kernel(bf16_t* __restrict__ gu) {
  size_t idx = (size_t)blockIdx.x * 256 + threadIdx.x;  // S*HID/8
  int r = (int)(idx / (HID_ / 8));
  int c8 = (int)(idx % (HID_ / 8));
  bf16_t* p = gu + (size_t)r * GU_N + c8 * 8;
  bf16x8 g8 = *(const bf16x8*)p;
  bf16x8 u8 = *(const bf16x8*)(p + HID_);
  bf16x8 h8;
  #pragma unroll
  for (int j = 0; j < 8; ++j) {
    float gv = (float)g8[j];
    float uv = (float)u8[j];
    h8[j] = (bf16_t)(gv / (1.f + __expf(-gv)) * uv);
  }
  *(bf16x8*)p = h8;
}

// ---------------------------------------------------------------- launch -----
extern "C" void kernel_launch(void* const* d_in, const int* in_sizes, int n_in,
                              void* d_out, int out_size, void* d_ws,
                              size_t ws_size, hipStream_t stream) {
  const float* x = (const float*)d_in[0];
  const int* pos = (const int*)d_in[1];
  const float* ln_w = (const float*)d_in[2];
  const float* ffln_w = (const float*)d_in[3];
  const float* wq = (const float*)d_in[4];
  const float* wk = (const float*)d_in[5];
  const float* wv = (const float*)d_in[6];
  const float* wo = (const float*)d_in[7];
  const float* wg = (const float*)d_in[8];
  const float* w1 = (const float*)d_in[9];
  const float* w2 = (const float*)d_in[10];

  char* ws = (char*)d_ws;
  size_t off = 0;
  auto alloc = [&](size_t bytes) {
    size_t o = off;
    off = (off + bytes + 255) & ~(size_t)255;
    return o;
  };
  bf16_t* Wbuf = (bf16_t*)(ws + alloc((size_t)GU_N * D_ * 2));  // ~172MB shared
  bf16_t* nbuf = (bf16_t*)(ws + alloc((size_t)S_ * D_ * 2));    // a / attn / b
  bf16_t* qkv  = (bf16_t*)(ws + alloc((size_t)S_ * QKV_N * 2));
  float*  x1   = (float*)(ws + alloc((size_t)S_ * D_ * 4));
  bf16_t* gu   = (bf16_t*)(ws + alloc((size_t)S_ * GU_N * 2));
  float*  cos_t = (float*)(ws + alloc((size_t)S_ * 64 * 4));
  float*  sin_t = (float*)(ws + alloc((size_t)S_ * 64 * 4));
  // split-K partial buffers in the unused tail of Wbuf (weights <= 96MB used).
  float* part = (float*)((char*)Wbuf + ((size_t)96 << 20));  // 2 x 32MB

  // 1. a = rmsnorm(x)
  rmsnorm_kernel<<<S_, 256, 0, stream>>>(x, ln_w, nbuf);
  // 2. W_qkv^T (bf16): rows 0..4095=wq^T, 4096..5119=wk^T, 5120..6143=wv^T
  wtrans_kernel<<<dim3(D_ / 32, D_ / 256), 256, 0, stream>>>(wq, Wbuf, D_, D_);
  wtrans_kernel<<<dim3(D_ / 32, 1024 / 256), 256, 0, stream>>>(
      wk, Wbuf + (size_t)4096 * D_, D_, 1024);
  wtrans_kernel<<<dim3(D_ / 32, 1024 / 256), 256, 0, stream>>>(
      wv, Wbuf + (size_t)5120 * D_, D_, 1024);
  rope_table_kernel<<<(S_ * 64) / 256, 256, 0, stream>>>(pos, cos_t, sin_t);
  // 3. qkv = a @ Wqkv   (grid 8x24 = 192)
  gemm256_kernel<0, 0><<<dim3((S_ / 256) * (QKV_N / 256)), 512, 0, stream>>>(
      nbuf, D_, Wbuf, D_, qkv, QKV_N, D_);
  // 4. rope q,k in-place
  rope_kernel<<<(S_ * H_ * 64) / 256, 256, 0, stream>>>(
      qkv, cos_t, sin_t, H_, 0, S_ * H_ * 64);
  rope_kernel<<<(S_ * KVH_ * 64) / 256, 256, 0, stream>>>(
      qkv, cos_t, sin_t, KVH_, 4096, S_ * KVH_ * 64);
  // 5. attention -> nbuf
  attn_kernel<<<dim3(S_ / 64, H_), 256, 0, stream>>>(qkv, nbuf);
  // 6. partials = attn @ wo (split-K 2x2048, 256 blocks)
  wtrans_kernel<<<dim3(D_ / 32, D_ / 256), 256, 0, stream>>>(wo, Wbuf, D_, D_);
  gemm256_kernel<2, 1><<<dim3((S_ / 256) * (D_ / 256) * 2), 512, 0, stream>>>(
      nbuf, D_, Wbuf, D_, part, D_, 2048);
  // 7. x1 = x + p0 + p1 ; b = rmsnorm(x1)
  combine_rms_kernel<<<S_, 256, 0, stream>>>(
      x, part, part + (size_t)S_ * D_, ffln_w, x1, nbuf);
  // 8. gu = b @ [wg|w1]   (grid 8x86 = 688)
  wtrans_kernel<<<dim3(D_ / 32, HID_ / 256), 256, 0, stream>>>(wg, Wbuf, D_, HID_);
  wtrans_kernel<<<dim3(D_ / 32, HID_ / 256), 256, 0, stream>>>(
      w1, Wbuf + (size_t)HID_ * D_, D_, HID_);
  gemm256_kernel<0, 0><<<dim3((S_ / 256) * (GU_N / 256)), 512, 0, stream>>>(
      nbuf, D_, Wbuf, D_, gu, GU_N, D_);
  // 9. h = silu(g)*u in-place (left half of gu)
  silu_mul_kernel<<<(S_ * HID_ / 8) / 256, 256, 0, stream>>>(gu);
  // 10. partials = h @ w2 (split-K 2x5504, 256 blocks)
  wtrans_kernel<<<dim3(HID_ / 32, D_ / 256), 256, 0, stream>>>(w2, Wbuf, HID_, D_);
  gemm256_kernel<2, 1><<<dim3((S_ / 256) * (D_ / 256) * 2), 512, 0, stream>>>(
      gu, GU_N, Wbuf, HID_, part, D_, 5504);
  // 11. out = x1 + p0 + p1
  combine_out_kernel<<<(S_ * D_ / 4) / 256, 256, 0, stream>>>(
      x1, part, part + (size_t)S_ * D_, (float*)d_out);
}

// Round 6
// 1394.355 us; speedup vs baseline: 1.0970x; 1.0970x over previous
//
#include <hip/hip_runtime.h>
#include <hip/hip_bf16.h>

typedef __bf16 bf16_t;
typedef __bf16 bf16x4 __attribute__((ext_vector_type(4)));
typedef __bf16 bf16x8 __attribute__((ext_vector_type(8)));
typedef float f32x4 __attribute__((ext_vector_type(4)));

#define S_ 2048
#define D_ 4096
#define H_ 32
#define KVH_ 8
#define DH_ 128
#define HID_ 11008
#define QKV_N 6144   // 4096 q + 1024 k + 1024 v
#define GU_N 22016   // 11008 g + 11008 u

__device__ __forceinline__ void gl16(const bf16_t* g, bf16_t* l) {
  __builtin_amdgcn_global_load_lds(
      (const __attribute__((address_space(1))) unsigned int*)g,
      (__attribute__((address_space(3))) unsigned int*)l, 16, 0, 0);
}

// ---------------------------------------------------------------- RMSNorm ----
__global__ __launch_bounds__(256) void rmsnorm_kernel(
    const float* __restrict__ x, const float* __restrict__ w,
    bf16_t* __restrict__ out) {
  int row = blockIdx.x;
  const float* xr = x + (size_t)row * D_;
  float ss = 0.f;
  #pragma unroll
  for (int it = 0; it < 4; ++it) {
    int i = threadIdx.x * 4 + it * 1024;
    float4 v = *(const float4*)(xr + i);
    ss += v.x * v.x + v.y * v.y + v.z * v.z + v.w * v.w;
  }
  #pragma unroll
  for (int off = 32; off; off >>= 1) ss += __shfl_xor(ss, off);
  __shared__ float s4[4];
  if ((threadIdx.x & 63) == 0) s4[threadIdx.x >> 6] = ss;
  __syncthreads();
  float tot = s4[0] + s4[1] + s4[2] + s4[3];
  float rinv = rsqrtf(tot / (float)D_ + 1e-5f);
  bf16_t* orow = out + (size_t)row * D_;
  #pragma unroll
  for (int it = 0; it < 4; ++it) {
    int i = threadIdx.x * 4 + it * 1024;
    float4 v = *(const float4*)(xr + i);
    orow[i + 0] = (bf16_t)(v.x * rinv * w[i + 0]);
    orow[i + 1] = (bf16_t)(v.y * rinv * w[i + 1]);
    orow[i + 2] = (bf16_t)(v.z * rinv * w[i + 2]);
    orow[i + 3] = (bf16_t)(v.w * rinv * w[i + 3]);
  }
}

// ----------------------- combine wo-partials + residual + RMSNorm ------------
__global__ __launch_bounds__(256) void combine_rms_kernel(
    const float* __restrict__ x, const float* __restrict__ p0,
    const float* __restrict__ p1, const float* __restrict__ w,
    float* __restrict__ x1, bf16_t* __restrict__ out) {
  int row = blockIdx.x;
  size_t base = (size_t)row * D_;
  float ss = 0.f;
  float4 vals[4];
  #pragma unroll
  for (int it = 0; it < 4; ++it) {
    int i = threadIdx.x * 4 + it * 1024;
    float4 a = *(const float4*)(x + base + i);
    float4 b = *(const float4*)(p0 + base + i);
    float4 c = *(const float4*)(p1 + base + i);
    float4 v;
    v.x = a.x + b.x + c.x; v.y = a.y + b.y + c.y;
    v.z = a.z + b.z + c.z; v.w = a.w + b.w + c.w;
    vals[it] = v;
    *(float4*)(x1 + base + i) = v;
    ss += v.x * v.x + v.y * v.y + v.z * v.z + v.w * v.w;
  }
  #pragma unroll
  for (int off = 32; off; off >>= 1) ss += __shfl_xor(ss, off);
  __shared__ float s4[4];
  if ((threadIdx.x & 63) == 0) s4[threadIdx.x >> 6] = ss;
  __syncthreads();
  float tot = s4[0] + s4[1] + s4[2] + s4[3];
  float rinv = rsqrtf(tot / (float)D_ + 1e-5f);
  #pragma unroll
  for (int it = 0; it < 4; ++it) {
    int i = threadIdx.x * 4 + it * 1024;
    float4 v = vals[it];
    out[base + i + 0] = (bf16_t)(v.x * rinv * w[i + 0]);
    out[base + i + 1] = (bf16_t)(v.y * rinv * w[i + 1]);
    out[base + i + 2] = (bf16_t)(v.z * rinv * w[i + 2]);
    out[base + i + 3] = (bf16_t)(v.w * rinv * w[i + 3]);
  }
}

// ----------------------------- combine w2-partials + residual -> d_out -------
__global__ __launch_bounds__(256) void combine_out_kernel(
    const float* __restrict__ x1, const float* __restrict__ p0,
    const float* __restrict__ p1, float* __restrict__ outp) {
  size_t i = ((size_t)blockIdx.x * 256 + threadIdx.x) * 4;
  float4 a = *(const float4*)(x1 + i);
  float4 b = *(const float4*)(p0 + i);
  float4 c = *(const float4*)(p1 + i);
  float4 v;
  v.x = a.x + b.x + c.x; v.y = a.y + b.y + c.y;
  v.z = a.z + b.z + c.z; v.w = a.w + b.w + c.w;
  *(float4*)(outp + i) = v;
}

// ------------------------------------------- weight transpose f32 -> bf16 ----
// [32][258] pad: 129-word row stride == 1 mod 32 -> conflict-free gather reads
__global__ __launch_bounds__(256) void wtrans_kernel(
    const float* __restrict__ W, bf16_t* __restrict__ WT, int K, int N) {
  __shared__ bf16_t t[32][258];
  int k0 = blockIdx.x * 32, n0 = blockIdx.y * 256;
  #pragma unroll
  for (int i = 0; i < 8; ++i) {
    int flat = i * 1024 + threadIdx.x * 4;
    int kk = flat >> 8, nn = flat & 255;
    float4 wv = *(const float4*)(W + (size_t)(k0 + kk) * N + n0 + nn);
    bf16_t* p = &t[kk][nn];
    p[0] = (bf16_t)wv.x; p[1] = (bf16_t)wv.y;
    p[2] = (bf16_t)wv.z; p[3] = (bf16_t)wv.w;
  }
  __syncthreads();
  int kc8 = (threadIdx.x & 3) * 8;
  #pragma unroll
  for (int i = 0; i < 4; ++i) {
    int nn = i * 64 + (threadIdx.x >> 2);
    bf16x8 vals;
    #pragma unroll
    for (int j = 0; j < 8; ++j) vals[j] = t[kc8 + j][nn];
    *(bf16x8*)(WT + (size_t)(n0 + nn) * K + k0 + kc8) = vals;
  }
}

// ------------------------------------------------------------- RoPE table ----
__global__ __launch_bounds__(256) void rope_table_kernel(
    const int* __restrict__ pos_ids, float* __restrict__ cos_t,
    float* __restrict__ sin_t) {
  int idx = blockIdx.x * 256 + threadIdx.x;  // S_*64
  int s = idx >> 6, i = idx & 63;
  float pos = (float)pos_ids[s];
  float inv_freq = exp2f(-(float)i * (13.287712379549449f / 64.0f));
  float ang = pos * inv_freq;
  cos_t[idx] = cosf(ang);
  sin_t[idx] = sinf(ang);
}

// --------------------------------------------- RoPE in-place on qkv buffer ---
__global__ __launch_bounds__(256) void rope_kernel(
    bf16_t* __restrict__ buf, const float* __restrict__ cos_t,
    const float* __restrict__ sin_t, int nheads, int colbase, int total) {
  int idx = blockIdx.x * 256 + threadIdx.x;
  if (idx >= total) return;
  int i = idx & 63;
  int t2 = idx >> 6;
  int s = t2 / nheads, h = t2 % nheads;
  size_t base = (size_t)s * QKV_N + colbase + h * 128 + 2 * i;
  float x1 = (float)buf[base], x2 = (float)buf[base + 1];
  float c = cos_t[s * 64 + i], sn = sin_t[s * 64 + i];
  buf[base]     = (bf16_t)(x1 * c - x2 * sn);
  buf[base + 1] = (bf16_t)(x1 * sn + x2 * c);
}

// ------------------------------------------------------- 256x256 GEMM --------
// C[2048][N] = A[2048][K+] (bf16) @ BT[N][K+] (bf16)
// MODE 0: bf16 out; MODE 2: f32 plain store (SPLIT partials).
// 8 waves (2Mx4N), BK=64, 2 K-tiles double-buffered, 4 phases/K-tile,
// counted vmcnt(8).
// LDS subtile [ab][h][kk] = [128 rows][4 chunk-slots of 16B], where the
// chunk stored at slot cpos of row R is c = (cpos - (R>>1)) & 3 (rotation).
// Staging: linear dest (tid*16B); source row = tid>>2 (quarter-wave = 4 rows
// x 64B contiguous -> round-4 coalescing), source chunk = ((tid&3)-(tid>>3))&3.
// Reads: lane (g,fr) reads row's chunk g at slot rc=(g+(fr>>1))&3 ->
// each wave64 read covers every 16B slot of its 1KB block exactly once ->
// inherent 2-way bank aliasing only (free per m136), zero measured conflicts.

#define VMW(N)                                          \
  asm volatile("s_waitcnt vmcnt(" #N ")" ::: "memory"); \
  __builtin_amdgcn_sched_barrier(0)

#define DO_PHASE(BI, KK, MH, DO_LDB, STAGE1, STAGE2, WAITCODE)             \
  {                                                                        \
    _Pragma("unroll") for (int m = 0; m < 4; ++m)                          \
      aF[m] = *(const bf16x8*)&lds[BI][0][wr][KK]                          \
          [((MH) * 64 + m * 16 + fr) * 32 + rc * 8];                       \
    if (DO_LDB) {                                                          \
      _Pragma("unroll") for (int n = 0; n < 4; ++n)                        \
        bF[n] = *(const bf16x8*)&lds[BI][1][wcH][KK]                       \
            [(wcL * 64 + n * 16 + fr) * 32 + rc * 8];                      \
    }                                                                      \
    STAGE1;                                                                \
    STAGE2;                                                                \
    asm volatile("" ::: "memory");                                         \
    __builtin_amdgcn_s_barrier();                                          \
    asm volatile("s_waitcnt lgkmcnt(0)" ::: "memory");                     \
    __builtin_amdgcn_sched_barrier(0);                                     \
    __builtin_amdgcn_s_setprio(1);                                         \
    _Pragma("unroll") for (int m = 0; m < 4; ++m)                          \
      _Pragma("unroll") for (int n = 0; n < 4; ++n)                        \
        acc[(MH) * 4 + m][n] = __builtin_amdgcn_mfma_f32_16x16x32_bf16(    \
            aF[m], bF[n], acc[(MH) * 4 + m][n], 0, 0, 0);                  \
    __builtin_amdgcn_s_setprio(0);                                         \
    __builtin_amdgcn_sched_barrier(0);                                     \
    WAITCODE;                                                              \
    asm volatile("" ::: "memory");                                         \
    __builtin_amdgcn_s_barrier();                                          \
    asm volatile("" ::: "memory");                                         \
  }

#define DO_TILE(BI, T)                                                     \
  {                                                                        \
    const int Tp1 = (T) + 1 < NT, Tp2 = (T) + 2 < NT;                      \
    DO_PHASE(BI, 0, 0, 1,                                                  \
             if (Tp1) stage(BI ^ 1, 0, 0, 1, (T) + 1),                     \
             if (Tp1) stage(BI ^ 1, 1, 0, 1, (T) + 1), );                  \
    DO_PHASE(BI, 0, 1, 0,                                                  \
             if (Tp1) stage(BI ^ 1, 0, 1, 1, (T) + 1),                     \
             if (Tp1) stage(BI ^ 1, 1, 1, 1, (T) + 1),                     \
             if (Tp1) { VMW(8); } else { VMW(0); });                       \
    DO_PHASE(BI, 1, 0, 1,                                                  \
             if (Tp2) stage(BI, 0, 0, 0, (T) + 2),                         \
             if (Tp2) stage(BI, 1, 0, 0, (T) + 2), );                      \
    DO_PHASE(BI, 1, 1, 0,                                                  \
             if (Tp2) stage(BI, 0, 1, 0, (T) + 2),                         \
             if (Tp2) stage(BI, 1, 1, 0, (T) + 2),                         \
             if (Tp2) { VMW(8); } else if (Tp1) { VMW(4); });              \
  }

template <int MODE, int SPLIT>
__global__ __launch_bounds__(512, 2) void gemm256_kernel(
    const bf16_t* __restrict__ A, int lda, const bf16_t* __restrict__ BT,
    int ldb, void* __restrict__ Cout, int ldc, int K) {
  // [buf][A=0/B=1][half(row-block)][kk][128 rows * 32 elems]  = 128 KiB
  __shared__ __align__(16) bf16_t lds[2][2][2][2][128 * 32];

  const int tid = threadIdx.x;
  const int lane = tid & 63;
  const int wid = tid >> 6;
  const int wr = wid >> 2;            // 0..1  (M half)
  const int wc = wid & 3;             // 0..3  (N quarter)
  const int wcH = wc >> 1, wcL = wc & 1;
  const int g = lane >> 4, fr = lane & 15;
  const int rc = (g + ((fr >> 1) & 3)) & 3;   // rotated read-chunk slot

  // XCD-aware bijective swizzle (grid % 8 == 0 for all launches)
  const int nwg = gridDim.x;
  const int orig = blockIdx.x;
  int wg = (orig & 7) * (nwg >> 3) + (orig >> 3);
  int kz = 0;
  if constexpr (SPLIT) {
    const int half = nwg >> 1;
    kz = wg >= half;
    wg -= kz * half;
  }
  const int bx = wg & 7;              // M blocks = 2048/256 = 8
  const int by = wg >> 3;
  const size_t row0 = (size_t)bx * 256, col0 = (size_t)by * 256;

  // staging: row-linear source, chunk rotated by (row>>1)
  const int srow = tid >> 2;
  const int schunk = ((tid & 3) - ((tid >> 3) & 3)) & 3;

  const size_t lda2 = (size_t)lda * 2, ldb2 = (size_t)ldb * 2;
  const size_t kzoff = (size_t)kz * K * 2;
  const char* aB0 =
      (const char*)A + (row0 + srow) * lda2 + schunk * 16 + kzoff;
  const char* aB1 = aB0 + (size_t)128 * lda2;
  const char* bB0 =
      (const char*)BT + (col0 + srow) * ldb2 + schunk * 16 + kzoff;
  const char* bB1 = bB0 + (size_t)128 * ldb2;

  auto stage = [&](int bi, int ab, int h, int kk, int kt) {
    const char* base = ab ? (h ? bB1 : bB0) : (h ? aB1 : aB0);
    gl16((const bf16_t*)(base + (size_t)kt * 128 + kk * 64),
         &lds[bi][ab][h][kk][tid * 8]);
  };

  f32x4 acc[8][4] = {};
  bf16x8 aF[4], bF[4];
  const int NT = K / 64;  // even for all our shapes

  // prologue: tile0 fully, tile1 kk0
  stage(0, 0, 0, 0, 0); stage(0, 1, 0, 0, 0);
  stage(0, 0, 1, 0, 0); stage(0, 1, 1, 0, 0);
  stage(0, 0, 0, 1, 0); stage(0, 1, 0, 1, 0);
  stage(0, 0, 1, 1, 0); stage(0, 1, 1, 1, 0);
  stage(1, 0, 0, 0, 1); stage(1, 1, 0, 0, 1);
  stage(1, 0, 1, 0, 1); stage(1, 1, 1, 0, 1);
  VMW(4);
  asm volatile("" ::: "memory");
  __builtin_amdgcn_s_barrier();
  asm volatile("" ::: "memory");

  for (int T = 0; T < NT; T += 2) {
    DO_TILE(0, T);
    DO_TILE(1, T + 1);
  }

  // epilogue
  float* fOut = (float*)Cout + (size_t)kz * 2048 * ldc;
  #pragma unroll
  for (int mf = 0; mf < 8; ++mf)
    #pragma unroll
    for (int n = 0; n < 4; ++n)
      #pragma unroll
      for (int r = 0; r < 4; ++r) {
        size_t row = row0 + wr * 128 + mf * 16 + g * 4 + r;
        size_t col = col0 + wc * 64 + n * 16 + fr;
        float val = acc[mf][n][r];
        if constexpr (MODE == 0) {
          ((bf16_t*)Cout)[row * ldc + col] = (bf16_t)val;
        } else {
          fOut[row * ldc + col] = val;
        }
      }
}

// ------------------------------------------------------- flash attention -----
__global__ __launch_bounds__(256) void attn_kernel(
    const bf16_t* __restrict__ qkv, bf16_t* __restrict__ o) {
  int h = blockIdx.y;
  int qb = blockIdx.x;
  int kvh = h >> 2;
  int wid = threadIdx.x >> 6, lane = threadIdx.x & 63;
  int g = lane >> 4, fr = lane & 15;

  __shared__ __align__(16) bf16_t k_lds[64][136];
  __shared__ __align__(16) bf16_t vt_lds[128][72];
  __shared__ __align__(16) bf16_t p_lds[4][16][72];

  int q0w = qb * 64 + wid * 16;
  bf16x8 q_frag[4];
  const bf16_t* qptr = qkv + (size_t)(q0w + fr) * QKV_N + h * 128;
  #pragma unroll
  for (int kc = 0; kc < 4; ++kc)
    q_frag[kc] = *(const bf16x8*)(qptr + kc * 32 + g * 8);

  f32x4 o_frag[8] = {};
  float m_run[4], l_run[4];
  #pragma unroll
  for (int r = 0; r < 4; ++r) { m_run[r] = -1e30f; l_run[r] = 0.f; }

  const float sc = 0.08838834764831845f * 1.4426950408889634f;

  for (int t = 0; t <= qb; ++t) {
    int kv0 = t * 64;
    __syncthreads();
    for (int i = threadIdx.x; i < 1024; i += 256) {
      int row = i >> 4, c8 = (i & 15) * 8;
      size_t base = (size_t)(kv0 + row) * QKV_N + kvh * 128 + c8;
      bf16x8 k8 = *(const bf16x8*)(qkv + base + 4096);
      *(bf16x8*)&k_lds[row][c8] = k8;
      bf16x8 v8 = *(const bf16x8*)(qkv + base + 5120);
      #pragma unroll
      for (int j = 0; j < 8; ++j) vt_lds[c8 + j][row] = v8[j];
    }
    __syncthreads();

    f32x4 sfr[4];
    #pragma unroll
    for (int nf = 0; nf < 4; ++nf) {
      f32x4 acc = {};
      #pragma unroll
      for (int kc = 0; kc < 4; ++kc) {
        bf16x8 kf = *(const bf16x8*)&k_lds[fr + 16 * nf][kc * 32 + g * 8];
        acc = __builtin_amdgcn_mfma_f32_16x16x32_bf16(q_frag[kc], kf, acc, 0, 0, 0);
      }
      sfr[nf] = acc;
    }

    bool diag = (t == qb);
    float mtile[4];
    #pragma unroll
    for (int r = 0; r < 4; ++r) mtile[r] = -1e30f;
    #pragma unroll
    for (int nf = 0; nf < 4; ++nf)
      #pragma unroll
      for (int r = 0; r < 4; ++r) {
        if (diag) {
          int kvg = kv0 + nf * 16 + fr;
          int qg = q0w + 4 * g + r;
          if (kvg > qg) sfr[nf][r] = -1e30f;
        }
        mtile[r] = fmaxf(mtile[r], sfr[nf][r]);
      }
    #pragma unroll
    for (int r = 0; r < 4; ++r) {
      float mv = mtile[r];
      mv = fmaxf(mv, __shfl_xor(mv, 1));
      mv = fmaxf(mv, __shfl_xor(mv, 2));
      mv = fmaxf(mv, __shfl_xor(mv, 4));
      mv = fmaxf(mv, __shfl_xor(mv, 8));
      mtile[r] = mv;
    }
    float alpha[4];
    #pragma unroll
    for (int r = 0; r < 4; ++r) {
      float m_new = fmaxf(m_run[r], mtile[r]);
      alpha[r] = exp2f((m_run[r] - m_new) * sc);
      m_run[r] = m_new;
    }
    float lsum[4] = {0.f, 0.f, 0.f, 0.f};
    #pragma unroll
    for (int nf = 0; nf < 4; ++nf)
      #pragma unroll
      for (int r = 0; r < 4; ++r) {
        float p = exp2f((sfr[nf][r] - m_run[r]) * sc);
        sfr[nf][r] = p;
        lsum[r] += p;
      }
    #pragma unroll
    for (int r = 0; r < 4; ++r) {
      float lv = lsum[r];
      lv += __shfl_xor(lv, 1);
      lv += __shfl_xor(lv, 2);
      lv += __shfl_xor(lv, 4);
      lv += __shfl_xor(lv, 8);
      l_run[r] = l_run[r] * alpha[r] + lv;
    }
    #pragma unroll
    for (int nfo = 0; nfo < 8; ++nfo)
      #pragma unroll
      for (int r = 0; r < 4; ++r) o_frag[nfo][r] *= alpha[r];

    #pragma unroll
    for (int nf = 0; nf < 4; ++nf)
      #pragma unroll
      for (int r = 0; r < 4; ++r)
        p_lds[wid][4 * g + r][nf * 16 + fr] = (bf16_t)sfr[nf][r];
    __syncthreads();

    #pragma unroll
    for (int kc = 0; kc < 2; ++kc) {
      bf16x8 pf = *(const bf16x8*)&p_lds[wid][fr][kc * 32 + g * 8];
      #pragma unroll
      for (int nfo = 0; nfo < 8; ++nfo) {
        bf16x8 vf = *(const bf16x8*)&vt_lds[nfo * 16 + fr][kc * 32 + g * 8];
        o_frag[nfo] = __builtin_amdgcn_mfma_f32_16x16x32_bf16(pf, vf, o_frag[nfo], 0, 0, 0);
      }
    }
  }

  #pragma unroll
  for (int nfo = 0; nfo < 8; ++nfo)
    #pragma unroll
    for (int r = 0; r < 4; ++r) {
      int qg = q0w + 4 * g + r;
      float val = o_frag[nfo][r] / l_run[r];
      o[(size_t)qg * (H_ * DH_) + h * DH_ + nfo * 16 + fr] = (bf16_t)val;
    }
}

// ---------------------------------------------- SiLU*mul in-place on gu ------
__global__ __launch_bounds__(256) void silu_mul_kernel(bf16_t* __restrict__ gu) {
  size_t idx = (size_t)blockIdx.x * 256 + threadIdx.x;  // S*HID/8
  int r = (int)(idx / (HID_ / 8));
  int c8 = (int)(idx % (HID_ / 8));
  bf16_t* p = gu + (size_t)r * GU_N + c8 * 8;
  bf16x8 g8 = *(const bf16x8*)p;
  bf16x8 u8 = *(const bf16x8*)(p + HID_);
  bf16x8 h8;
  #pragma unroll
  for (int j = 0; j < 8; ++j) {
    float gv = (float)g8[j];
    float uv = (float)u8[j];
    h8[j] = (bf16_t)(gv / (1.f + __expf(-gv)) * uv);
  }
  *(bf16x8*)p = h8;
}

// ---------------------------------------------------------------- launch -----
extern "C" void kernel_launch(void* const* d_in, const int* in_sizes, int n_in,
                              void* d_out, int out_size, void* d_ws,
                              size_t ws_size, hipStream_t stream) {
  const float* x = (const float*)d_in[0];
  const int* pos = (const int*)d_in[1];
  const float* ln_w = (const float*)d_in[2];
  const float* ffln_w = (const float*)d_in[3];
  const float* wq = (const float*)d_in[4];
  const float* wk = (const float*)d_in[5];
  const float* wv = (const float*)d_in[6];
  const float* wo = (const float*)d_in[7];
  const float* wg = (const float*)d_in[8];
  const float* w1 = (const float*)d_in[9];
  const float* w2 = (const float*)d_in[10];

  char* ws = (char*)d_ws;
  size_t off = 0;
  auto alloc = [&](size_t bytes) {
    size_t o = off;
    off = (off + bytes + 255) & ~(size_t)255;
    return o;
  };
  bf16_t* Wbuf = (bf16_t*)(ws + alloc((size_t)GU_N * D_ * 2));  // ~172MB shared
  bf16_t* nbuf = (bf16_t*)(ws + alloc((size_t)S_ * D_ * 2));    // a / attn / b
  bf16_t* qkv  = (bf16_t*)(ws + alloc((size_t)S_ * QKV_N * 2));
  float*  x1   = (float*)(ws + alloc((size_t)S_ * D_ * 4));
  bf16_t* gu   = (bf16_t*)(ws + alloc((size_t)S_ * GU_N * 2));
  float*  cos_t = (float*)(ws + alloc((size_t)S_ * 64 * 4));
  float*  sin_t = (float*)(ws + alloc((size_t)S_ * 64 * 4));
  // split-K partial buffers in the unused tail of Wbuf (weights <= 96MB used).
  float* part = (float*)((char*)Wbuf + ((size_t)96 << 20));  // 2 x 32MB

  // 1. a = rmsnorm(x)
  rmsnorm_kernel<<<S_, 256, 0, stream>>>(x, ln_w, nbuf);
  // 2. W_qkv^T (bf16): rows 0..4095=wq^T, 4096..5119=wk^T, 5120..6143=wv^T
  wtrans_kernel<<<dim3(D_ / 32, D_ / 256), 256, 0, stream>>>(wq, Wbuf, D_, D_);
  wtrans_kernel<<<dim3(D_ / 32, 1024 / 256), 256, 0, stream>>>(
      wk, Wbuf + (size_t)4096 * D_, D_, 1024);
  wtrans_kernel<<<dim3(D_ / 32, 1024 / 256), 256, 0, stream>>>(
      wv, Wbuf + (size_t)5120 * D_, D_, 1024);
  rope_table_kernel<<<(S_ * 64) / 256, 256, 0, stream>>>(pos, cos_t, sin_t);
  // 3. qkv = a @ Wqkv   (grid 8x24 = 192)
  gemm256_kernel<0, 0><<<dim3((S_ / 256) * (QKV_N / 256)), 512, 0, stream>>>(
      nbuf, D_, Wbuf, D_, qkv, QKV_N, D_);
  // 4. rope q,k in-place
  rope_kernel<<<(S_ * H_ * 64) / 256, 256, 0, stream>>>(
      qkv, cos_t, sin_t, H_, 0, S_ * H_ * 64);
  rope_kernel<<<(S_ * KVH_ * 64) / 256, 256, 0, stream>>>(
      qkv, cos_t, sin_t, KVH_, 4096, S_ * KVH_ * 64);
  // 5. attention -> nbuf
  attn_kernel<<<dim3(S_ / 64, H_), 256, 0, stream>>>(qkv, nbuf);
  // 6. partials = attn @ wo (split-K 2x2048, 256 blocks)
  wtrans_kernel<<<dim3(D_ / 32, D_ / 256), 256, 0, stream>>>(wo, Wbuf, D_, D_);
  gemm256_kernel<2, 1><<<dim3((S_ / 256) * (D_ / 256) * 2), 512, 0, stream>>>(
      nbuf, D_, Wbuf, D_, part, D_, 2048);
  // 7. x1 = x + p0 + p1 ; b = rmsnorm(x1)
  combine_rms_kernel<<<S_, 256, 0, stream>>>(
      x, part, part + (size_t)S_ * D_, ffln_w, x1, nbuf);
  // 8. gu = b @ [wg|w1]   (grid 8x86 = 688)
  wtrans_kernel<<<dim3(D_ / 32, HID_ / 256), 256, 0, stream>>>(wg, Wbuf, D_, HID_);
  wtrans_kernel<<<dim3(D_ / 32, HID_ / 256), 256, 0, stream>>>(
      w1, Wbuf + (size_t)HID_ * D_, D_, HID_);
  gemm256_kernel<0, 0><<<dim3((S_ / 256) * (GU_N / 256)), 512, 0, stream>>>(
      nbuf, D_, Wbuf, D_, gu, GU_N, D_);
  // 9. h = silu(g)*u in-place (left half of gu)
  silu_mul_kernel<<<(S_ * HID_ / 8) / 256, 256, 0, stream>>>(gu);
  // 10. partials = h @ w2 (split-K 2x5504, 256 blocks)
  wtrans_kernel<<<dim3(HID_ / 32, D_ / 256), 256, 0, stream>>>(w2, Wbuf, HID_, D_);
  gemm256_kernel<2, 1><<<dim3((S_ / 256) * (D_ / 256) * 2), 512, 0, stream>>>(
      gu, GU_N, Wbuf, HID_, part, D_, 5504);
  // 11. out = x1 + p0 + p1
  combine_out_kernel<<<(S_ * D_ / 4) / 256, 256, 0, stream>>>(
      x1, part, part + (size_t)S_ * D_, (float*)d_out);
}

// Round 7
// 1194.712 us; speedup vs baseline: 1.2803x; 1.1671x over previous
//
#include <hip/hip_runtime.h>
#include <hip/hip_bf16.h>

typedef __bf16 bf16_t;
typedef __bf16 bf16x4 __attribute__((ext_vector_type(4)));
typedef __bf16 bf16x8 __attribute__((ext_vector_type(8)));
typedef float f32x4 __attribute__((ext_vector_type(4)));

#define S_ 2048
#define D_ 4096
#define H_ 32
#define KVH_ 8
#define DH_ 128
#define HID_ 11008
#define QKV_N 6144   // 4096 q + 1024 k + 1024 v
#define GU_N 22016   // 11008 g + 11008 u

__device__ __forceinline__ void gl16(const bf16_t* g, bf16_t* l) {
  __builtin_amdgcn_global_load_lds(
      (const __attribute__((address_space(1))) unsigned int*)g,
      (__attribute__((address_space(3))) unsigned int*)l, 16, 0, 0);
}

#define VMW(N)                                          \
  asm volatile("s_waitcnt vmcnt(" #N ")" ::: "memory"); \
  __builtin_amdgcn_sched_barrier(0)

#define BAR()                          \
  asm volatile("" ::: "memory");       \
  __builtin_amdgcn_s_barrier();        \
  asm volatile("" ::: "memory")

// ---------------------------------------------------------------- RMSNorm ----
__global__ __launch_bounds__(256) void rmsnorm_kernel(
    const float* __restrict__ x, const float* __restrict__ w,
    bf16_t* __restrict__ out) {
  int row = blockIdx.x;
  const float* xr = x + (size_t)row * D_;
  float ss = 0.f;
  #pragma unroll
  for (int it = 0; it < 4; ++it) {
    int i = threadIdx.x * 4 + it * 1024;
    float4 v = *(const float4*)(xr + i);
    ss += v.x * v.x + v.y * v.y + v.z * v.z + v.w * v.w;
  }
  #pragma unroll
  for (int off = 32; off; off >>= 1) ss += __shfl_xor(ss, off);
  __shared__ float s4[4];
  if ((threadIdx.x & 63) == 0) s4[threadIdx.x >> 6] = ss;
  __syncthreads();
  float tot = s4[0] + s4[1] + s4[2] + s4[3];
  float rinv = rsqrtf(tot / (float)D_ + 1e-5f);
  bf16_t* orow = out + (size_t)row * D_;
  #pragma unroll
  for (int it = 0; it < 4; ++it) {
    int i = threadIdx.x * 4 + it * 1024;
    float4 v = *(const float4*)(xr + i);
    orow[i + 0] = (bf16_t)(v.x * rinv * w[i + 0]);
    orow[i + 1] = (bf16_t)(v.y * rinv * w[i + 1]);
    orow[i + 2] = (bf16_t)(v.z * rinv * w[i + 2]);
    orow[i + 3] = (bf16_t)(v.w * rinv * w[i + 3]);
  }
}

// ----------------------- combine wo-partials + residual + RMSNorm ------------
__global__ __launch_bounds__(256) void combine_rms_kernel(
    const float* __restrict__ x, const float* __restrict__ p0,
    const float* __restrict__ p1, const float* __restrict__ w,
    float* __restrict__ x1, bf16_t* __restrict__ out) {
  int row = blockIdx.x;
  size_t base = (size_t)row * D_;
  float ss = 0.f;
  float4 vals[4];
  #pragma unroll
  for (int it = 0; it < 4; ++it) {
    int i = threadIdx.x * 4 + it * 1024;
    float4 a = *(const float4*)(x + base + i);
    float4 b = *(const float4*)(p0 + base + i);
    float4 c = *(const float4*)(p1 + base + i);
    float4 v;
    v.x = a.x + b.x + c.x; v.y = a.y + b.y + c.y;
    v.z = a.z + b.z + c.z; v.w = a.w + b.w + c.w;
    vals[it] = v;
    *(float4*)(x1 + base + i) = v;
    ss += v.x * v.x + v.y * v.y + v.z * v.z + v.w * v.w;
  }
  #pragma unroll
  for (int off = 32; off; off >>= 1) ss += __shfl_xor(ss, off);
  __shared__ float s4[4];
  if ((threadIdx.x & 63) == 0) s4[threadIdx.x >> 6] = ss;
  __syncthreads();
  float tot = s4[0] + s4[1] + s4[2] + s4[3];
  float rinv = rsqrtf(tot / (float)D_ + 1e-5f);
  #pragma unroll
  for (int it = 0; it < 4; ++it) {
    int i = threadIdx.x * 4 + it * 1024;
    float4 v = vals[it];
    out[base + i + 0] = (bf16_t)(v.x * rinv * w[i + 0]);
    out[base + i + 1] = (bf16_t)(v.y * rinv * w[i + 1]);
    out[base + i + 2] = (bf16_t)(v.z * rinv * w[i + 2]);
    out[base + i + 3] = (bf16_t)(v.w * rinv * w[i + 3]);
  }
}

// ----------------------------- combine w2-partials + residual -> d_out -------
__global__ __launch_bounds__(256) void combine_out_kernel(
    const float* __restrict__ x1, const float* __restrict__ p0,
    const float* __restrict__ p1, float* __restrict__ outp) {
  size_t i = ((size_t)blockIdx.x * 256 + threadIdx.x) * 4;
  float4 a = *(const float4*)(x1 + i);
  float4 b = *(const float4*)(p0 + i);
  float4 c = *(const float4*)(p1 + i);
  float4 v;
  v.x = a.x + b.x + c.x; v.y = a.y + b.y + c.y;
  v.z = a.z + b.z + c.z; v.w = a.w + b.w + c.w;
  *(float4*)(outp + i) = v;
}

// ------------------------------------------- weight transpose f32 -> bf16 ----
__global__ __launch_bounds__(256) void wtrans_kernel(
    const float* __restrict__ W, bf16_t* __restrict__ WT, int K, int N) {
  __shared__ bf16_t t[32][258];
  int k0 = blockIdx.x * 32, n0 = blockIdx.y * 256;
  #pragma unroll
  for (int i = 0; i < 8; ++i) {
    int flat = i * 1024 + threadIdx.x * 4;
    int kk = flat >> 8, nn = flat & 255;
    float4 wv = *(const float4*)(W + (size_t)(k0 + kk) * N + n0 + nn);
    bf16_t* p = &t[kk][nn];
    p[0] = (bf16_t)wv.x; p[1] = (bf16_t)wv.y;
    p[2] = (bf16_t)wv.z; p[3] = (bf16_t)wv.w;
  }
  __syncthreads();
  int kc8 = (threadIdx.x & 3) * 8;
  #pragma unroll
  for (int i = 0; i < 4; ++i) {
    int nn = i * 64 + (threadIdx.x >> 2);
    bf16x8 vals;
    #pragma unroll
    for (int j = 0; j < 8; ++j) vals[j] = t[kc8 + j][nn];
    *(bf16x8*)(WT + (size_t)(n0 + nn) * K + k0 + kc8) = vals;
  }
}

// ------------------------------------- V transpose: qkv v-part -> vt[d][s] ---
__global__ __launch_bounds__(256) void vtrans_kernel(
    const bf16_t* __restrict__ qkv, bf16_t* __restrict__ vt) {
  __shared__ bf16_t t[64][72];
  int s0 = blockIdx.x * 64, d0 = blockIdx.y * 64;
  #pragma unroll
  for (int it = 0; it < 2; ++it) {
    int r = (threadIdx.x >> 3) + it * 32;
    int c = (threadIdx.x & 7) * 8;
    *(bf16x8*)&t[r][c] =
        *(const bf16x8*)(qkv + (size_t)(s0 + r) * QKV_N + 5120 + d0 + c);
  }
  __syncthreads();
  #pragma unroll
  for (int it = 0; it < 2; ++it) {
    int c = threadIdx.x & 63;
    int sb = (threadIdx.x >> 6) * 16 + it * 8;
    bf16x8 v;
    #pragma unroll
    for (int j = 0; j < 8; ++j) v[j] = t[sb + j][c];
    *(bf16x8*)(vt + (size_t)(d0 + c) * S_ + s0 + sb) = v;
  }
}

// ------------------------------------------------------------- RoPE table ----
__global__ __launch_bounds__(256) void rope_table_kernel(
    const int* __restrict__ pos_ids, float* __restrict__ cos_t,
    float* __restrict__ sin_t) {
  int idx = blockIdx.x * 256 + threadIdx.x;  // S_*64
  int s = idx >> 6, i = idx & 63;
  float pos = (float)pos_ids[s];
  float inv_freq = exp2f(-(float)i * (13.287712379549449f / 64.0f));
  float ang = pos * inv_freq;
  cos_t[idx] = cosf(ang);
  sin_t[idx] = sinf(ang);
}

// --------------------------------------------- RoPE in-place on qkv buffer ---
__global__ __launch_bounds__(256) void rope_kernel(
    bf16_t* __restrict__ buf, const float* __restrict__ cos_t,
    const float* __restrict__ sin_t, int nheads, int colbase, int total) {
  int idx = blockIdx.x * 256 + threadIdx.x;
  if (idx >= total) return;
  int i = idx & 63;
  int t2 = idx >> 6;
  int s = t2 / nheads, h = t2 % nheads;
  size_t base = (size_t)s * QKV_N + colbase + h * 128 + 2 * i;
  float x1 = (float)buf[base], x2 = (float)buf[base + 1];
  float c = cos_t[s * 64 + i], sn = sin_t[s * 64 + i];
  buf[base]     = (bf16_t)(x1 * c - x2 * sn);
  buf[base + 1] = (bf16_t)(x1 * sn + x2 * c);
}

// ------------------------------------------------------- 256x256 GEMM --------
// (unchanged from round 6 — zero-conflict chunk-rotation layout)
#define DO_PHASE(BI, KK, MH, DO_LDB, STAGE1, STAGE2, WAITCODE)             \
  {                                                                        \
    _Pragma("unroll") for (int m = 0; m < 4; ++m)                          \
      aF[m] = *(const bf16x8*)&lds[BI][0][wr][KK]                          \
          [((MH) * 64 + m * 16 + fr) * 32 + rc * 8];                       \
    if (DO_LDB) {                                                          \
      _Pragma("unroll") for (int n = 0; n < 4; ++n)                        \
        bF[n] = *(const bf16x8*)&lds[BI][1][wcH][KK]                       \
            [(wcL * 64 + n * 16 + fr) * 32 + rc * 8];                      \
    }                                                                      \
    STAGE1;                                                                \
    STAGE2;                                                                \
    asm volatile("" ::: "memory");                                         \
    __builtin_amdgcn_s_barrier();                                          \
    asm volatile("s_waitcnt lgkmcnt(0)" ::: "memory");                     \
    __builtin_amdgcn_sched_barrier(0);                                     \
    __builtin_amdgcn_s_setprio(1);                                         \
    _Pragma("unroll") for (int m = 0; m < 4; ++m)                          \
      _Pragma("unroll") for (int n = 0; n < 4; ++n)                        \
        acc[(MH) * 4 + m][n] = __builtin_amdgcn_mfma_f32_16x16x32_bf16(    \
            aF[m], bF[n], acc[(MH) * 4 + m][n], 0, 0, 0);                  \
    __builtin_amdgcn_s_setprio(0);                                         \
    __builtin_amdgcn_sched_barrier(0);                                     \
    WAITCODE;                                                              \
    asm volatile("" ::: "memory");                                         \
    __builtin_amdgcn_s_barrier();                                          \
    asm volatile("" ::: "memory");                                         \
  }

#define DO_TILE(BI, T)                                                     \
  {                                                                        \
    const int Tp1 = (T) + 1 < NT, Tp2 = (T) + 2 < NT;                      \
    DO_PHASE(BI, 0, 0, 1,                                                  \
             if (Tp1) stage(BI ^ 1, 0, 0, 1, (T) + 1),                     \
             if (Tp1) stage(BI ^ 1, 1, 0, 1, (T) + 1), );                  \
    DO_PHASE(BI, 0, 1, 0,                                                  \
             if (Tp1) stage(BI ^ 1, 0, 1, 1, (T) + 1),                     \
             if (Tp1) stage(BI ^ 1, 1, 1, 1, (T) + 1),                     \
             if (Tp1) { VMW(8); } else { VMW(0); });                       \
    DO_PHASE(BI, 1, 0, 1,                                                  \
             if (Tp2) stage(BI, 0, 0, 0, (T) + 2),                         \
             if (Tp2) stage(BI, 1, 0, 0, (T) + 2), );                      \
    DO_PHASE(BI, 1, 1, 0,                                                  \
             if (Tp2) stage(BI, 0, 1, 0, (T) + 2),                         \
             if (Tp2) stage(BI, 1, 1, 0, (T) + 2),                         \
             if (Tp2) { VMW(8); } else if (Tp1) { VMW(4); });              \
  }

template <int MODE, int SPLIT>
__global__ __launch_bounds__(512, 2) void gemm256_kernel(
    const bf16_t* __restrict__ A, int lda, const bf16_t* __restrict__ BT,
    int ldb, void* __restrict__ Cout, int ldc, int K) {
  __shared__ __align__(16) bf16_t lds[2][2][2][2][128 * 32];

  const int tid = threadIdx.x;
  const int lane = tid & 63;
  const int wid = tid >> 6;
  const int wr = wid >> 2;
  const int wc = wid & 3;
  const int wcH = wc >> 1, wcL = wc & 1;
  const int g = lane >> 4, fr = lane & 15;
  const int rc = (g + ((fr >> 1) & 3)) & 3;

  const int nwg = gridDim.x;
  const int orig = blockIdx.x;
  int wg = (orig & 7) * (nwg >> 3) + (orig >> 3);
  int kz = 0;
  if constexpr (SPLIT) {
    const int half = nwg >> 1;
    kz = wg >= half;
    wg -= kz * half;
  }
  const int bx = wg & 7;
  const int by = wg >> 3;
  const size_t row0 = (size_t)bx * 256, col0 = (size_t)by * 256;

  const int srow = tid >> 2;
  const int schunk = ((tid & 3) - ((tid >> 3) & 3)) & 3;

  const size_t lda2 = (size_t)lda * 2, ldb2 = (size_t)ldb * 2;
  const size_t kzoff = (size_t)kz * K * 2;
  const char* aB0 =
      (const char*)A + (row0 + srow) * lda2 + schunk * 16 + kzoff;
  const char* aB1 = aB0 + (size_t)128 * lda2;
  const char* bB0 =
      (const char*)BT + (col0 + srow) * ldb2 + schunk * 16 + kzoff;
  const char* bB1 = bB0 + (size_t)128 * ldb2;

  auto stage = [&](int bi, int ab, int h, int kk, int kt) {
    const char* base = ab ? (h ? bB1 : bB0) : (h ? aB1 : aB0);
    gl16((const bf16_t*)(base + (size_t)kt * 128 + kk * 64),
         &lds[bi][ab][h][kk][tid * 8]);
  };

  f32x4 acc[8][4] = {};
  bf16x8 aF[4], bF[4];
  const int NT = K / 64;

  stage(0, 0, 0, 0, 0); stage(0, 1, 0, 0, 0);
  stage(0, 0, 1, 0, 0); stage(0, 1, 1, 0, 0);
  stage(0, 0, 0, 1, 0); stage(0, 1, 0, 1, 0);
  stage(0, 0, 1, 1, 0); stage(0, 1, 1, 1, 0);
  stage(1, 0, 0, 0, 1); stage(1, 1, 0, 0, 1);
  stage(1, 0, 1, 0, 1); stage(1, 1, 1, 0, 1);
  VMW(4);
  BAR();

  for (int T = 0; T < NT; T += 2) {
    DO_TILE(0, T);
    DO_TILE(1, T + 1);
  }

  float* fOut = (float*)Cout + (size_t)kz * 2048 * ldc;
  #pragma unroll
  for (int mf = 0; mf < 8; ++mf)
    #pragma unroll
    for (int n = 0; n < 4; ++n)
      #pragma unroll
      for (int r = 0; r < 4; ++r) {
        size_t row = row0 + wr * 128 + mf * 16 + g * 4 + r;
        size_t col = col0 + wc * 64 + n * 16 + fr;
        float val = acc[mf][n][r];
        if constexpr (MODE == 0) {
          ((bf16_t*)Cout)[row * ldc + col] = (bf16_t)val;
        } else {
          fOut[row * ldc + col] = val;
        }
      }
}

// ------------------------------------------------------- flash attention -----
// grid (32 qb, 32 h), 4 waves. K and V^T staged via global_load_lds into
// lane-ordered fragment blocks (zero-conflict ds_read_b128), double-buffered
// with counted vmcnt(8). V^T comes from the pre-transposed vt buffer.
__global__ __launch_bounds__(256, 2) void attn_kernel(
    const bf16_t* __restrict__ qkv, const bf16_t* __restrict__ vt,
    bf16_t* __restrict__ o) {
  int h = blockIdx.y;
  int qb = (S_ / 64 - 1) - blockIdx.x;  // longest blocks dispatch first
  int kvh = h >> 2;
  int tid = threadIdx.x;
  int wid = tid >> 6, lane = tid & 63;
  int g = lane >> 4, fr = lane & 15;

  // fragment-block LDS: slot s (16B) holds, for K: kv=nf*16+fr', d-chunk
  // kc*4+g' where s = nf*256 + kc*64 + fr'*4 + g'; for VT: d=nfo*16+fr',
  // kv-chunk kc2*4+g' where s = nfo*128 + kc2*64 + fr'*4 + g'.
  __shared__ __align__(16) bf16_t kfl[2][8192];
  __shared__ __align__(16) bf16_t vfl[2][8192];
  __shared__ __align__(16) bf16_t p_lds[4][16][72];

  // staging decomposition (thread -> slot i*256+tid)
  const int fr_s = (tid >> 2) & 15, g_s = tid & 3;
  const int kcw = (tid >> 6) & 3;   // K d-chunk quad (= wave id)
  const int kc2w = (tid >> 6) & 1;  // VT kv-chunk pair
  const int nhi = tid >> 7;
  const bf16_t* kSrc = qkv + (size_t)fr_s * QKV_N + 4096 + kvh * 128 +
                       (kcw * 4 + g_s) * 8;
  const bf16_t* vSrc = vt + ((size_t)kvh * 128 + nhi * 16 + fr_s) * S_ +
                       (kc2w * 4 + g_s) * 8;

  auto stage = [&](int bi, int t) {
    size_t kv0 = (size_t)t * 64;
    #pragma unroll
    for (int i = 0; i < 4; ++i)
      gl16(kSrc + (kv0 + i * 16) * QKV_N, &kfl[bi][(i * 256 + tid) * 8]);
    #pragma unroll
    for (int i = 0; i < 4; ++i)
      gl16(vSrc + (size_t)i * 32 * S_ + kv0, &vfl[bi][(i * 256 + tid) * 8]);
  };

  int q0w = qb * 64 + wid * 16;
  bf16x8 q_frag[4];
  const bf16_t* qptr = qkv + (size_t)(q0w + fr) * QKV_N + h * 128;
  #pragma unroll
  for (int kc = 0; kc < 4; ++kc)
    q_frag[kc] = *(const bf16x8*)(qptr + kc * 32 + g * 8);
  VMW(0);  // q_frag landed; keep manual vmcnt accounting exact

  stage(0, 0);

  f32x4 o_frag[8] = {};
  float m_run[4], l_run[4];
  #pragma unroll
  for (int r = 0; r < 4; ++r) { m_run[r] = -1e30f; l_run[r] = 0.f; }

  const float sc = 0.08838834764831845f * 1.4426950408889634f;

  for (int t = 0; t <= qb; ++t) {
    int cur = t & 1;
    int kv0 = t * 64;
    if (t < qb) {
      stage(cur ^ 1, t + 1);
      VMW(8);
    } else {
      VMW(0);
    }
    BAR();  // all waves' tile-t staging landed

    // S = Q @ K^T  (per wave: 16 q x 64 kv)
    f32x4 sfr[4];
    #pragma unroll
    for (int nf = 0; nf < 4; ++nf) {
      f32x4 acc = {};
      #pragma unroll
      for (int kc = 0; kc < 4; ++kc) {
        bf16x8 kf =
            *(const bf16x8*)&kfl[cur][(nf * 256 + kc * 64 + fr * 4 + g) * 8];
        acc = __builtin_amdgcn_mfma_f32_16x16x32_bf16(q_frag[kc], kf, acc, 0, 0, 0);
      }
      sfr[nf] = acc;
    }

    bool diag = (t == qb);
    float mtile[4];
    #pragma unroll
    for (int r = 0; r < 4; ++r) mtile[r] = -1e30f;
    #pragma unroll
    for (int nf = 0; nf < 4; ++nf)
      #pragma unroll
      for (int r = 0; r < 4; ++r) {
        if (diag) {
          int kvg = kv0 + nf * 16 + fr;
          int qg = q0w + 4 * g + r;
          if (kvg > qg) sfr[nf][r] = -1e30f;
        }
        mtile[r] = fmaxf(mtile[r], sfr[nf][r]);
      }
    #pragma unroll
    for (int r = 0; r < 4; ++r) {
      float mv = mtile[r];
      mv = fmaxf(mv, __shfl_xor(mv, 1));
      mv = fmaxf(mv, __shfl_xor(mv, 2));
      mv = fmaxf(mv, __shfl_xor(mv, 4));
      mv = fmaxf(mv, __shfl_xor(mv, 8));
      mtile[r] = mv;
    }
    float alpha[4];
    #pragma unroll
    for (int r = 0; r < 4; ++r) {
      float m_new = fmaxf(m_run[r], mtile[r]);
      alpha[r] = exp2f((m_run[r] - m_new) * sc);
      m_run[r] = m_new;
    }
    float lsum[4] = {0.f, 0.f, 0.f, 0.f};
    #pragma unroll
    for (int nf = 0; nf < 4; ++nf)
      #pragma unroll
      for (int r = 0; r < 4; ++r) {
        float p = exp2f((sfr[nf][r] - m_run[r]) * sc);
        sfr[nf][r] = p;
        lsum[r] += p;
      }
    #pragma unroll
    for (int r = 0; r < 4; ++r) {
      float lv = lsum[r];
      lv += __shfl_xor(lv, 1);
      lv += __shfl_xor(lv, 2);
      lv += __shfl_xor(lv, 4);
      lv += __shfl_xor(lv, 8);
      l_run[r] = l_run[r] * alpha[r] + lv;
    }
    #pragma unroll
    for (int nfo = 0; nfo < 8; ++nfo)
      #pragma unroll
      for (int r = 0; r < 4; ++r) o_frag[nfo][r] *= alpha[r];

    // P -> per-wave LDS (A-operand bounce)
    #pragma unroll
    for (int nf = 0; nf < 4; ++nf)
      #pragma unroll
      for (int r = 0; r < 4; ++r)
        p_lds[wid][4 * g + r][nf * 16 + fr] = (bf16_t)sfr[nf][r];

    // O += P @ V
    #pragma unroll
    for (int kc2 = 0; kc2 < 2; ++kc2) {
      bf16x8 pf = *(const bf16x8*)&p_lds[wid][fr][kc2 * 32 + g * 8];
      #pragma unroll
      for (int nfo = 0; nfo < 8; ++nfo) {
        bf16x8 vf =
            *(const bf16x8*)&vfl[cur][(nfo * 128 + kc2 * 64 + fr * 4 + g) * 8];
        o_frag[nfo] = __builtin_amdgcn_mfma_f32_16x16x32_bf16(pf, vf, o_frag[nfo], 0, 0, 0);
      }
    }
    BAR();  // all waves done reading tile t before it is overwritten
  }

  #pragma unroll
  for (int nfo = 0; nfo < 8; ++nfo)
    #pragma unroll
    for (int r = 0; r < 4; ++r) {
      int qg = q0w + 4 * g + r;
      float val = o_frag[nfo][r] / l_run[r];
      o[(size_t)qg * (H_ * DH_) + h * DH_ + nfo * 16 + fr] = (bf16_t)val;
    }
}

// ---------------------------------------------- SiLU*mul in-place on gu ------
__global__ __launch_bounds__(256) void silu_mul_kernel(bf16_t* __restrict__ gu) {
  size_t idx = (size_t)blockIdx.x * 256 + threadIdx.x;  // S*HID/8
  int r = (int)(idx / (HID_ / 8));
  int c8 = (int)(idx % (HID_ / 8));
  bf16_t* p = gu + (size_t)r * GU_N + c8 * 8;
  bf16x8 g8 = *(const bf16x8*)p;
  bf16x8 u8 = *(const bf16x8*)(p + HID_);
  bf16x8 h8;
  #pragma unroll
  for (int j = 0; j < 8; ++j) {
    float gv = (float)g8[j];
    float uv = (float)u8[j];
    h8[j] = (bf16_t)(gv / (1.f + __expf(-gv)) * uv);
  }
  *(bf16x8*)p = h8;
}

// ---------------------------------------------------------------- launch -----
extern "C" void kernel_launch(void* const* d_in, const int* in_sizes, int n_in,
                              void* d_out, int out_size, void* d_ws,
                              size_t ws_size, hipStream_t stream) {
  const float* x = (const float*)d_in[0];
  const int* pos = (const int*)d_in[1];
  const float* ln_w = (const float*)d_in[2];
  const float* ffln_w = (const float*)d_in[3];
  const float* wq = (const float*)d_in[4];
  const float* wk = (const float*)d_in[5];
  const float* wv = (const float*)d_in[6];
  const float* wo = (const float*)d_in[7];
  const float* wg = (const float*)d_in[8];
  const float* w1 = (const float*)d_in[9];
  const float* w2 = (const float*)d_in[10];

  char* ws = (char*)d_ws;
  size_t off = 0;
  auto alloc = [&](size_t bytes) {
    size_t o = off;
    off = (off + bytes + 255) & ~(size_t)255;
    return o;
  };
  bf16_t* Wbuf = (bf16_t*)(ws + alloc((size_t)GU_N * D_ * 2));  // ~172MB shared
  bf16_t* nbuf = (bf16_t*)(ws + alloc((size_t)S_ * D_ * 2));    // a / attn / b
  bf16_t* qkv  = (bf16_t*)(ws + alloc((size_t)S_ * QKV_N * 2));
  float*  x1   = (float*)(ws + alloc((size_t)S_ * D_ * 4));
  bf16_t* gu   = (bf16_t*)(ws + alloc((size_t)S_ * GU_N * 2));
  bf16_t* vtb  = (bf16_t*)(ws + alloc((size_t)KVH_ * DH_ * S_ * 2));  // 4MB
  float*  cos_t = (float*)(ws + alloc((size_t)S_ * 64 * 4));
  float*  sin_t = (float*)(ws + alloc((size_t)S_ * 64 * 4));
  // split-K partial buffers in the unused tail of Wbuf (weights <= 96MB used).
  float* part = (float*)((char*)Wbuf + ((size_t)96 << 20));  // 2 x 32MB

  // 1. a = rmsnorm(x)
  rmsnorm_kernel<<<S_, 256, 0, stream>>>(x, ln_w, nbuf);
  // 2. W_qkv^T (bf16): rows 0..4095=wq^T, 4096..5119=wk^T, 5120..6143=wv^T
  wtrans_kernel<<<dim3(D_ / 32, D_ / 256), 256, 0, stream>>>(wq, Wbuf, D_, D_);
  wtrans_kernel<<<dim3(D_ / 32, 1024 / 256), 256, 0, stream>>>(
      wk, Wbuf + (size_t)4096 * D_, D_, 1024);
  wtrans_kernel<<<dim3(D_ / 32, 1024 / 256), 256, 0, stream>>>(
      wv, Wbuf + (size_t)5120 * D_, D_, 1024);
  rope_table_kernel<<<(S_ * 64) / 256, 256, 0, stream>>>(pos, cos_t, sin_t);
  // 3. qkv = a @ Wqkv
  gemm256_kernel<0, 0><<<dim3((S_ / 256) * (QKV_N / 256)), 512, 0, stream>>>(
      nbuf, D_, Wbuf, D_, qkv, QKV_N, D_);
  // 4. rope q,k in-place ; V^T
  rope_kernel<<<(S_ * H_ * 64) / 256, 256, 0, stream>>>(
      qkv, cos_t, sin_t, H_, 0, S_ * H_ * 64);
  rope_kernel<<<(S_ * KVH_ * 64) / 256, 256, 0, stream>>>(
      qkv, cos_t, sin_t, KVH_, 4096, S_ * KVH_ * 64);
  vtrans_kernel<<<dim3(S_ / 64, (KVH_ * DH_) / 64), 256, 0, stream>>>(qkv, vtb);
  // 5. attention -> nbuf
  attn_kernel<<<dim3(S_ / 64, H_), 256, 0, stream>>>(qkv, vtb, nbuf);
  // 6. partials = attn @ wo (split-K 2x2048, 256 blocks)
  wtrans_kernel<<<dim3(D_ / 32, D_ / 256), 256, 0, stream>>>(wo, Wbuf, D_, D_);
  gemm256_kernel<2, 1><<<dim3((S_ / 256) * (D_ / 256) * 2), 512, 0, stream>>>(
      nbuf, D_, Wbuf, D_, part, D_, 2048);
  // 7. x1 = x + p0 + p1 ; b = rmsnorm(x1)
  combine_rms_kernel<<<S_, 256, 0, stream>>>(
      x, part, part + (size_t)S_ * D_, ffln_w, x1, nbuf);
  // 8. gu = b @ [wg|w1]
  wtrans_kernel<<<dim3(D_ / 32, HID_ / 256), 256, 0, stream>>>(wg, Wbuf, D_, HID_);
  wtrans_kernel<<<dim3(D_ / 32, HID_ / 256), 256, 0, stream>>>(
      w1, Wbuf + (size_t)HID_ * D_, D_, HID_);
  gemm256_kernel<0, 0><<<dim3((S_ / 256) * (GU_N / 256)), 512, 0, stream>>>(
      nbuf, D_, Wbuf, D_, gu, GU_N, D_);
  // 9. h = silu(g)*u in-place (left half of gu)
  silu_mul_kernel<<<(S_ * HID_ / 8) / 256, 256, 0, stream>>>(gu);
  // 10. partials = h @ w2 (split-K 2x5504, 256 blocks)
  wtrans_kernel<<<dim3(HID_ / 32, D_ / 256), 256, 0, stream>>>(w2, Wbuf, HID_, D_);
  gemm256_kernel<2, 1><<<dim3((S_ / 256) * (D_ / 256) * 2), 512, 0, stream>>>(
      gu, GU_N, Wbuf, HID_, part, D_, 5504);
  // 11. out = x1 + p0 + p1
  combine_out_kernel<<<(S_ * D_ / 4) / 256, 256, 0, stream>>>(
      x1, part, part + (size_t)S_ * D_, (float*)d_out);
}